// Round 14
// baseline (534.954 us; speedup 1.0000x reference)
//
#include <hip/hip_runtime.h>
#include <hip/hip_bf16.h>
#include <cstdint>
#include <cstddef>

#define HD   256
#define NV   50000
#define NE   80000
#define NNZC 400000
#define FINC 512
#define NCLS 40

using bf16 = __hip_bfloat16;

typedef short bf16x8v __attribute__((ext_vector_type(8)));
typedef float f32x4   __attribute__((ext_vector_type(4)));
typedef unsigned short u16x8 __attribute__((ext_vector_type(8)));

#define NCH_E ((NE + 1023) / 1024)   // 79
#define NCH_V ((NV + 1023) / 1024)   // 49
#define NBM_V ((NV + 127) / 128)     // 391 row-blocks for NV GEMMs

// ---------- dtype helpers ----------
__device__ __forceinline__ float b2f(unsigned short u) {
    union { unsigned int i; float f; } c; c.i = ((unsigned int)u) << 16; return c.f;
}
__device__ __forceinline__ unsigned short f2b(float f) {
    union { float f; unsigned int i; } c; c.f = f;
    return (unsigned short)((c.i + 0x7FFFu + ((c.i >> 16) & 1u)) >> 16);
}
__device__ __forceinline__ float4 load4f(const bf16* p) {
    ushort4 u = *reinterpret_cast<const ushort4*>(p);
    return make_float4(b2f(u.x), b2f(u.y), b2f(u.z), b2f(u.w));
}
__device__ __forceinline__ void store4(bf16* p, float4 v) {
    ushort4 u; u.x = f2b(v.x); u.y = f2b(v.y); u.z = f2b(v.z); u.w = f2b(v.w);
    *reinterpret_cast<ushort4*>(p) = u;
}

// ---------- async global->LDS, 16B per lane (bf16 staging only; r6 lesson) ----------
__device__ __forceinline__ void gl_lds16(const bf16* g, short* l) {
    __builtin_amdgcn_global_load_lds(
        (const __attribute__((address_space(1))) unsigned int*)g,
        (__attribute__((address_space(3))) unsigned int*)l,
        16, 0, 0);
}

// ---------- gather body (shared by solo + fused kernels) ----------
__device__ __forceinline__ void gather_body(const bf16* __restrict__ src,
                                            const int* __restrict__ adj,
                                            const int* __restrict__ off,
                                            bf16* __restrict__ dst,
                                            int seg, int lane)
{
    int s0 = off[seg], s1 = off[seg + 1];
    float4 acc = make_float4(0.f, 0.f, 0.f, 0.f);
    int j = s0;
    for (; j + 4 <= s1; j += 4) {
        int r0 = adj[j], r1 = adj[j + 1], r2 = adj[j + 2], r3 = adj[j + 3];
        float4 v0 = load4f(src + (size_t)r0 * HD + lane * 4);
        float4 v1 = load4f(src + (size_t)r1 * HD + lane * 4);
        float4 v2 = load4f(src + (size_t)r2 * HD + lane * 4);
        float4 v3 = load4f(src + (size_t)r3 * HD + lane * 4);
        acc.x += (v0.x + v1.x) + (v2.x + v3.x);
        acc.y += (v0.y + v1.y) + (v2.y + v3.y);
        acc.z += (v0.z + v1.z) + (v2.z + v3.z);
        acc.w += (v0.w + v1.w) + (v2.w + v3.w);
    }
    for (; j < s1; ++j) {
        float4 v = load4f(src + (size_t)adj[j] * HD + lane * 4);
        acc.x += v.x; acc.y += v.y; acc.z += v.z; acc.w += v.w;
    }
    store4(dst + (size_t)seg * HD + lane * 4, acc);
}

// ---------- merged capture-safe fill + weight prep ----------
// blocks [0,128): zero-fill cnt_e++cnt_v ; blocks [128,128+1841): prep_w body
__global__ __launch_bounds__(256)
void fill_prep_k(unsigned int* __restrict__ fillp, long long filln,
                 const float* __restrict__ lin_w, const float* __restrict__ w1,
                 const float* __restrict__ w2, const float* __restrict__ w3,
                 const float* __restrict__ cw1, const float* __restrict__ cw2,
                 const float* __restrict__ b2,
                 unsigned short* __restrict__ lin_wt, unsigned short* __restrict__ w1_nb,
                 unsigned short* __restrict__ w2a_nb, unsigned short* __restrict__ w2b_nb,
                 unsigned short* __restrict__ w3t, unsigned short* __restrict__ cw1t,
                 unsigned short* __restrict__ cw2t, float* __restrict__ b2w3)
{
    if (blockIdx.x < 128) {
        long long i = (long long)blockIdx.x * 256 + threadIdx.x;
        for (; i < filln; i += 128 * 256) fillp[i] = 0u;
        return;
    }
    int idx = (blockIdx.x - 128) * 256 + threadIdx.x;  // < 471296
    if (idx < 131072) { int n = idx >> 9, k = idx & 511; lin_wt[idx] = f2b(lin_w[k * 256 + n]); return; }
    idx -= 131072;
    if (idx < 65536) { w1_nb[idx] = f2b(w1[idx]); return; }
    idx -= 65536;
    if (idx < 65536) { w2a_nb[idx] = f2b(w2[idx]); return; }
    idx -= 65536;
    if (idx < 65536) { w2b_nb[idx] = f2b(w2[65536 + idx]); return; }
    idx -= 65536;
    if (idx < 65536) { int n = idx >> 8, k = idx & 255; w3t[idx] = f2b(w3[k * 256 + n]); return; }
    idx -= 65536;
    if (idx < 65536) { int n = idx >> 8, k = idx & 255; cw1t[idx] = f2b(cw1[k * 256 + n]); return; }
    idx -= 65536;
    if (idx < 12288) { int n = idx >> 8, k = idx & 255; cw2t[idx] = f2b((n < NCLS) ? cw2[k * NCLS + n] : 0.f); return; }
    idx -= 12288;
    if (idx < 256) {
        float s = 0.f;
        for (int k = 0; k < 256; ++k) s += b2[k] * w3[k * 256 + idx];
        b2w3[idx] = s;
    }
}

// ---------- combined histogram ----------
__global__ __launch_bounds__(256)
void hist_k(const int* __restrict__ vertex, const int* __restrict__ edges,
            int* __restrict__ cnt_v, int* __restrict__ cnt_e, int nnz)
{
    int i = blockIdx.x * 256 + threadIdx.x;
    if (i < nnz) {
        atomicAdd(&cnt_v[vertex[i]], 1);
        atomicAdd(&cnt_e[edges[i]], 1);
    }
}

// ---------- merged 3-phase scan (y=0: edges, y=1: vertices) ----------
__global__ __launch_bounds__(256)
void scan_part2_k(const int* __restrict__ cnt_e, int* __restrict__ off_e, int* __restrict__ part_e,
                  const int* __restrict__ cnt_v, int* __restrict__ off_v, int* __restrict__ part_v)
{
    const int* cnt; int* off; int* part; int n;
    if (blockIdx.y == 0) { cnt = cnt_e; off = off_e; part = part_e; n = NE; }
    else                 { cnt = cnt_v; off = off_v; part = part_v; n = NV; }
    int base = blockIdx.x * 1024;
    if (base >= n) return;
    __shared__ int s[256];
    int idx = base + threadIdx.x * 4;
    int v[4], sum = 0;
    #pragma unroll
    for (int j = 0; j < 4; ++j) { v[j] = (idx + j < n) ? cnt[idx + j] : 0; sum += v[j]; }
    s[threadIdx.x] = sum;
    __syncthreads();
    #pragma unroll
    for (int d = 1; d < 256; d <<= 1) {
        int t = (threadIdx.x >= d) ? s[threadIdx.x - d] : 0;
        __syncthreads();
        s[threadIdx.x] += t;
        __syncthreads();
    }
    int excl = s[threadIdx.x] - sum;
    #pragma unroll
    for (int j = 0; j < 4; ++j) {
        if (idx + j < n) off[idx + j] = excl;
        excl += v[j];
    }
    if (threadIdx.x == 255) part[blockIdx.x] = s[255];
}

__global__ __launch_bounds__(256)
void scan_top2_k(int* __restrict__ part_e, int* __restrict__ end_e,
                 int* __restrict__ part_v, int* __restrict__ end_v)
{
    int* part; int* endp; int nch;
    if (blockIdx.x == 0) { part = part_e; endp = end_e; nch = NCH_E; }
    else                 { part = part_v; endp = end_v; nch = NCH_V; }
    __shared__ int s[256];
    int v = (threadIdx.x < nch) ? part[threadIdx.x] : 0;
    s[threadIdx.x] = v;
    __syncthreads();
    #pragma unroll
    for (int d = 1; d < 256; d <<= 1) {
        int t = (threadIdx.x >= d) ? s[threadIdx.x - d] : 0;
        __syncthreads();
        s[threadIdx.x] += t;
        __syncthreads();
    }
    if (threadIdx.x < nch) part[threadIdx.x] = s[threadIdx.x] - v;
    if (threadIdx.x == 255) *endp = s[255];
}

__global__ __launch_bounds__(256)
void scan_addcur2_k(int* __restrict__ off_e, const int* __restrict__ part_e, int* __restrict__ cur_e,
                    int* __restrict__ off_v, const int* __restrict__ part_v, int* __restrict__ cur_v)
{
    int n; int* off; const int* part; int* cur;
    if (blockIdx.y == 0) { n = NE; off = off_e; part = part_e; cur = cur_e; }
    else                 { n = NV; off = off_v; part = part_v; cur = cur_v; }
    int i = blockIdx.x * 256 + threadIdx.x;
    if (i < n) { int o = off[i] + part[i >> 10]; off[i] = o; cur[i] = o; }
}

// ---------- CSR adjacency fill ----------
__global__ __launch_bounds__(256)
void csr_fill_k(const int* __restrict__ vertex, const int* __restrict__ edges,
                int* __restrict__ cur_e, int* __restrict__ cur_v,
                int* __restrict__ adj_e, int* __restrict__ adj_v, int nnz)
{
    int i = blockIdx.x * 256 + threadIdx.x;
    if (i >= nnz) return;
    int v = vertex[i], e = edges[i];
    adj_e[atomicAdd(&cur_e[e], 1)] = v;
    adj_v[atomicAdd(&cur_v[v], 1)] = e;
}

// ---------- dege2[v] = sum_{e in adj_v[v]} cnt_e[e] ----------
__global__ __launch_bounds__(256)
void dege2_k(const int* __restrict__ cnt_e, const int* __restrict__ adj_v,
             const int* __restrict__ off_v, int* __restrict__ dege2, int n)
{
    int v = blockIdx.x * 256 + threadIdx.x;
    if (v >= n) return;
    int s = 0;
    for (int j = off_v[v]; j < off_v[v + 1]; ++j) s += cnt_e[adj_v[j]];
    dege2[v] = s;
}

// ---------- b1w23[n] = sum_k b1[k] * W23b[k][n] ----------
__global__ __launch_bounds__(256)
void b1w23_k(const float* __restrict__ b1, const unsigned short* __restrict__ W23bt,
             float* __restrict__ o)
{
    int n = threadIdx.x;
    float s = 0.f;
    for (int k = 0; k < 256; ++k) s += b1[k] * b2f(W23bt[n * 256 + k]);
    o[n] = s;
}

// ---------- MFMA bf16 GEMM: 128x128 tile, BK=64, 4 waves (r9-verified core) ----------
// EPI 0/1: row-major (+bias)(+relu). EPI 3: row-major multi-split.
// EPI 5: PERM split store (see r13). EPI 4: perm S/z0 HOISTED before K-loop (r14).
template<int EPI, bool AF32>
__global__ __launch_bounds__(256)
void mgemm_k(const void* __restrict__ Agv, const bf16* __restrict__ Bt,
             const float* __restrict__ bias, const float* __restrict__ bias2,
             const int* __restrict__ deg, const int* __restrict__ dege2,
             const bf16* __restrict__ Sb, const bf16* __restrict__ z0b,
             const float* __restrict__ b2w3v, const float* __restrict__ b1w23v,
             bf16* __restrict__ Cg, bf16* __restrict__ Cg2, bf16* __restrict__ Cg3,
             int M, int K, int Nc)
{
    const int nbn = Nc >> 7;
    const int nbm = (M + 127) >> 7;
    const int p   = blockIdx.x;
    const int xcd = p & 7;
    const int q   = p >> 3;
    const int cblk = q % nbn;
    const int rblk = q / nbn;
    const int rb   = rblk * 8 + xcd;
    if (rb >= nbm) return;
    const int bn = cblk * 128;
    const int bm = rb * 128;

    __shared__ __align__(16) short As[128 * 64];
    __shared__ __align__(16) short Bs[128 * 64];

    const int t  = threadIdx.x;
    const int wv = t >> 6, l = t & 63;
    const int wr = wv >> 1, wc = wv & 1;
    const int l15 = l & 15;

    // ---- EPI4: issue S/z0 perm loads + bias loads EARLY (hide under K-loop) ----
    u16x8 sv8[8], zv8[8];
    float bv[4], bw[4], bb1[4];
    if (EPI == 4) {
        const unsigned short* Sp = (const unsigned short*)Sb + ((size_t)(rb * 2 + cblk) * 256 + t) * 64;
        const unsigned short* Zp = (const unsigned short*)z0b + ((size_t)(rb * 2 + cblk) * 256 + t) * 64;
        #pragma unroll
        for (int j = 0; j < 8; ++j) {
            sv8[j] = *reinterpret_cast<const u16x8*>(Sp + j * 8);
            zv8[j] = *reinterpret_cast<const u16x8*>(Zp + j * 8);
        }
        #pragma unroll
        for (int n = 0; n < 4; ++n) {
            int col = bn + wc * 64 + n * 16 + l15;
            bv[n]  = bias[col];
            bw[n]  = b2w3v[col];
            bb1[n] = b1w23v[col];
        }
    }

    f32x4 acc[4][4];
    #pragma unroll
    for (int m = 0; m < 4; ++m)
        #pragma unroll
        for (int n = 0; n < 4; ++n)
            acc[m][n] = (f32x4){0.f, 0.f, 0.f, 0.f};

    const int brow8   = l >> 3;
    const int bcol_sw = (((l & 7) ^ (l >> 3)) * 8);

    for (int k0 = 0; k0 < K; k0 += 64) {
        if constexpr (AF32) {
            const float* Af = (const float*)Agv;
            #pragma unroll
            for (int pi = 0; pi < 4; ++pi) {
                int idx8 = pi * 256 + t;
                int row  = idx8 >> 3;
                int cg   = (idx8 & 7) * 8;
                int ga = bm + row; if (ga >= M) ga = M - 1;
                const float* src = Af + (size_t)ga * K + k0 + cg;
                f32x4 u = *reinterpret_cast<const f32x4*>(src);
                f32x4 v = *reinterpret_cast<const f32x4*>(src + 4);
                bf16x8v o;
                o[0] = (short)f2b(u[0]); o[1] = (short)f2b(u[1]);
                o[2] = (short)f2b(u[2]); o[3] = (short)f2b(u[3]);
                o[4] = (short)f2b(v[0]); o[5] = (short)f2b(v[1]);
                o[6] = (short)f2b(v[2]); o[7] = (short)f2b(v[3]);
                *reinterpret_cast<bf16x8v*>(As + row * 64 + (cg ^ ((row & 7) * 8))) = o;
            }
        } else {
            const bf16* Ab = (const bf16*)Agv;
            #pragma unroll
            for (int i = 0; i < 4; ++i) {
                int c = wv * 4 + i;
                int row = c * 8 + brow8;
                int ga = bm + row; if (ga >= M) ga = M - 1;
                gl_lds16(Ab + (size_t)ga * K + k0 + bcol_sw, As + c * 512);
            }
        }
        #pragma unroll
        for (int i = 0; i < 4; ++i) {
            int c = wv * 4 + i;
            int row = c * 8 + brow8;
            gl_lds16(Bt + (size_t)(bn + row) * K + k0 + bcol_sw, Bs + c * 512);
        }
        __syncthreads();

        #pragma unroll
        for (int ks = 0; ks < 2; ++ks) {
            bf16x8v a[4], b[4];
            const int kb = ks * 64 + (l >> 4) * 16;
            #pragma unroll
            for (int m = 0; m < 4; ++m) {
                int r = wr * 64 + m * 16 + l15;
                a[m] = *reinterpret_cast<const bf16x8v*>(
                           (const char*)As + r * 128 + (kb ^ ((r & 7) << 4)));
            }
            #pragma unroll
            for (int n = 0; n < 4; ++n) {
                int r = wc * 64 + n * 16 + l15;
                b[n] = *reinterpret_cast<const bf16x8v*>(
                           (const char*)Bs + r * 128 + (kb ^ ((r & 7) << 4)));
            }
            #pragma unroll
            for (int m = 0; m < 4; ++m)
                #pragma unroll
                for (int n = 0; n < 4; ++n)
                    acc[m][n] = __builtin_amdgcn_mfma_f32_16x16x32_bf16(a[m], b[n], acc[m][n], 0, 0, 0);
        }
        __syncthreads();
    }

    if (EPI == 5) {
        int oi = bn >> 8;
        bf16* CC = (oi == 0) ? Cg : Cg2;
        int c2 = (bn >> 7) & 1;
        unsigned short* P = (unsigned short*)CC + ((size_t)(rb * 2 + c2) * 256 + t) * 64;
        #pragma unroll
        for (int m = 0; m < 4; ++m) {
            u16x8 o0, o1;
            #pragma unroll
            for (int n = 0; n < 2; ++n)
                #pragma unroll
                for (int i = 0; i < 4; ++i) {
                    o0[n * 4 + i] = f2b(acc[m][n][i]);
                    o1[n * 4 + i] = f2b(acc[m][n + 2][i]);
                }
            *reinterpret_cast<u16x8*>(P + m * 16)     = o0;
            *reinterpret_cast<u16x8*>(P + m * 16 + 8) = o1;
        }
    } else if (EPI == 4) {
        #pragma unroll
        for (int m = 0; m < 4; ++m) {
            #pragma unroll
            for (int i = 0; i < 4; ++i) {
                int row = bm + wr * 64 + m * 16 + (l >> 4) * 4 + i;
                if (row >= M) continue;
                float d   = (float)deg[row];
                float de2 = (float)dege2[row];
                size_t base = (size_t)row * Nc + bn + wc * 64 + l15;
                #pragma unroll
                for (int n = 0; n < 4; ++n) {
                    int e = m * 16 + n * 4 + i;
                    float sv = b2f(sv8[e >> 3][e & 7]);
                    float zv = b2f(zv8[e >> 3][e & 7]);
                    float v = 0.5f * (d * (sv + bw[n]) + acc[m][n][i] + de2 * bb1[n])
                              + 0.5f * zv + bv[n];
                    v = fmaxf(v, 0.f);
                    reinterpret_cast<unsigned short*>(Cg)[base + (size_t)n * 16] = f2b(v);
                }
            }
        }
    } else if (EPI == 3) {
        int oi = bn >> 8;
        bf16* CC = (oi == 0) ? Cg : (oi == 1) ? Cg2 : Cg3;
        const float* bb = (oi == 0) ? bias : (oi == 1) ? bias2 : nullptr;
        int cb = bn & 255;
        float bvv[4];
        #pragma unroll
        for (int n = 0; n < 4; ++n)
            bvv[n] = bb ? bb[cb + wc * 64 + n * 16 + l15] : 0.f;
        #pragma unroll
        for (int m = 0; m < 4; ++m) {
            #pragma unroll
            for (int i = 0; i < 4; ++i) {
                int row = bm + wr * 64 + m * 16 + (l >> 4) * 4 + i;
                if (row >= M) continue;
                size_t base = (size_t)row * 256 + cb + wc * 64 + l15;
                #pragma unroll
                for (int n = 0; n < 4; ++n)
                    reinterpret_cast<unsigned short*>(CC)[base + n * 16] = f2b(acc[m][n][i] + bvv[n]);
            }
        }
    } else {
        float bvv[4];
        #pragma unroll
        for (int n = 0; n < 4; ++n)
            bvv[n] = bias ? bias[bn + wc * 64 + n * 16 + l15] : 0.f;
        #pragma unroll
        for (int m = 0; m < 4; ++m) {
            #pragma unroll
            for (int i = 0; i < 4; ++i) {
                int row = bm + wr * 64 + m * 16 + (l >> 4) * 4 + i;
                if (row >= M) continue;
                size_t base = (size_t)row * Nc + bn + wc * 64 + l15;
                #pragma unroll
                for (int n = 0; n < 4; ++n) {
                    float v = acc[m][n][i] + bvv[n];
                    if (EPI == 1) v = fmaxf(v, 0.f);
                    reinterpret_cast<unsigned short*>(Cg)[base + n * 16] = f2b(v);
                }
            }
        }
    }
}

// ---------- fused dispatch: S-GEMM (EPI5, blocks < gemmBlocks) || gather_e ----------
// Roles are block-uniform; GEMM barriers are block-local; writes disjoint (S/z0 vs E2).
__global__ __launch_bounds__(256)
void fusedA_k(const bf16* __restrict__ Ag, const bf16* __restrict__ Bt,
              bf16* __restrict__ Sg, bf16* __restrict__ z0g,
              int M, int K, int Nc, int gemmBlocks,
              const bf16* __restrict__ gsrc, const int* __restrict__ adj,
              const int* __restrict__ off, bf16* __restrict__ gdst, int nseg)
{
    __shared__ __align__(16) short As[128 * 64];
    __shared__ __align__(16) short Bs[128 * 64];
    const int t = threadIdx.x;

    if ((int)blockIdx.x >= gemmBlocks) {
        int seg = (blockIdx.x - gemmBlocks) * 4 + (t >> 6);
        if (seg < nseg) gather_body(gsrc, adj, off, gdst, seg, t & 63);
        return;
    }

    const int nbn = Nc >> 7;
    const int nbm = (M + 127) >> 7;
    const int p   = blockIdx.x;
    const int xcd = p & 7;
    const int q   = p >> 3;
    const int cblk = q % nbn;
    const int rblk = q / nbn;
    const int rb   = rblk * 8 + xcd;
    if (rb >= nbm) return;
    const int bn = cblk * 128;
    const int bm = rb * 128;

    const int wv = t >> 6, l = t & 63;
    const int wr = wv >> 1, wc = wv & 1;
    const int l15 = l & 15;

    f32x4 acc[4][4];
    #pragma unroll
    for (int m = 0; m < 4; ++m)
        #pragma unroll
        for (int n = 0; n < 4; ++n)
            acc[m][n] = (f32x4){0.f, 0.f, 0.f, 0.f};

    const int brow8   = l >> 3;
    const int bcol_sw = (((l & 7) ^ (l >> 3)) * 8);

    for (int k0 = 0; k0 < K; k0 += 64) {
        #pragma unroll
        for (int i = 0; i < 4; ++i) {
            int c = wv * 4 + i;
            int row = c * 8 + brow8;
            int ga = bm + row; if (ga >= M) ga = M - 1;
            gl_lds16(Ag + (size_t)ga * K + k0 + bcol_sw, As + c * 512);
        }
        #pragma unroll
        for (int i = 0; i < 4; ++i) {
            int c = wv * 4 + i;
            int row = c * 8 + brow8;
            gl_lds16(Bt + (size_t)(bn + row) * K + k0 + bcol_sw, Bs + c * 512);
        }
        __syncthreads();

        #pragma unroll
        for (int ks = 0; ks < 2; ++ks) {
            bf16x8v a[4], b[4];
            const int kb = ks * 64 + (l >> 4) * 16;
            #pragma unroll
            for (int m = 0; m < 4; ++m) {
                int r = wr * 64 + m * 16 + l15;
                a[m] = *reinterpret_cast<const bf16x8v*>(
                           (const char*)As + r * 128 + (kb ^ ((r & 7) << 4)));
            }
            #pragma unroll
            for (int n = 0; n < 4; ++n) {
                int r = wc * 64 + n * 16 + l15;
                b[n] = *reinterpret_cast<const bf16x8v*>(
                           (const char*)Bs + r * 128 + (kb ^ ((r & 7) << 4)));
            }
            #pragma unroll
            for (int m = 0; m < 4; ++m)
                #pragma unroll
                for (int n = 0; n < 4; ++n)
                    acc[m][n] = __builtin_amdgcn_mfma_f32_16x16x32_bf16(a[m], b[n], acc[m][n], 0, 0, 0);
        }
        __syncthreads();
    }

    // EPI5 perm split store
    int oi = bn >> 8;
    bf16* CC = (oi == 0) ? Sg : z0g;
    int c2 = (bn >> 7) & 1;
    unsigned short* P = (unsigned short*)CC + ((size_t)(rb * 2 + c2) * 256 + t) * 64;
    #pragma unroll
    for (int m = 0; m < 4; ++m) {
        u16x8 o0, o1;
        #pragma unroll
        for (int n = 0; n < 2; ++n)
            #pragma unroll
            for (int i = 0; i < 4; ++i) {
                o0[n * 4 + i] = f2b(acc[m][n][i]);
                o1[n * 4 + i] = f2b(acc[m][n + 2][i]);
            }
        *reinterpret_cast<u16x8*>(P + m * 16)     = o0;
        *reinterpret_cast<u16x8*>(P + m * 16 + 8) = o1;
    }
}

// ---------- solo gather (for gather_v) ----------
__global__ __launch_bounds__(256)
void gather_sum_k(const bf16* __restrict__ src, const int* __restrict__ adj,
                  const int* __restrict__ off, bf16* __restrict__ dst, int nseg)
{
    int seg = blockIdx.x * 4 + (threadIdx.x >> 6);
    if (seg >= nseg) return;
    gather_body(src, adj, off, dst, seg, threadIdx.x & 63);
}

// ---------- MFMA classifier ----------
__global__ __launch_bounds__(256)
void cls_mfma_k(const bf16* __restrict__ Hm, const bf16* __restrict__ Wt,
                const float* __restrict__ bias, float* __restrict__ out, int M)
{
    const int wv = threadIdx.x >> 6, l = threadIdx.x & 63;
    const int l15 = l & 15;
    const int r0 = blockIdx.x * 64 + wv * 16;
    f32x4 acc[3];
    #pragma unroll
    for (int n = 0; n < 3; ++n) acc[n] = (f32x4){0.f, 0.f, 0.f, 0.f};

    int arow = r0 + l15; if (arow >= M) arow = M - 1;
    const int ko = (l >> 4) * 8;
    for (int kk = 0; kk < HD; kk += 32) {
        bf16x8v a = *reinterpret_cast<const bf16x8v*>(Hm + (size_t)arow * HD + kk + ko);
        #pragma unroll
        for (int n = 0; n < 3; ++n) {
            bf16x8v b = *reinterpret_cast<const bf16x8v*>(Wt + (size_t)(n * 16 + l15) * HD + kk + ko);
            acc[n] = __builtin_amdgcn_mfma_f32_16x16x32_bf16(a, b, acc[n], 0, 0, 0);
        }
    }
    #pragma unroll
    for (int n = 0; n < 3; ++n) {
        int col = n * 16 + l15;
        if (col >= NCLS) continue;
        float bv = bias[col];
        #pragma unroll
        for (int i = 0; i < 4; ++i) {
            int row = r0 + (l >> 4) * 4 + i;
            if (row < M) out[(size_t)row * NCLS + col] = acc[n][i] + bv;
        }
    }
}

static inline int xcd_grid(int M, int Nc)
{
    int nbm = (M + 127) >> 7;
    int nbn = Nc >> 7;
    return nbn * (((nbm + 7) / 8) * 8);
}

extern "C" void kernel_launch(void* const* d_in, const int* in_sizes, int n_in,
                              void* d_out, int out_size, void* d_ws, size_t ws_size,
                              hipStream_t stream)
{
    const float* x_in   = (const float*)d_in[0];
    const int*   vertex = (const int*)d_in[1];
    const int*   edges  = (const int*)d_in[2];
    const float* lin_w  = (const float*)d_in[3];
    const float* lin_b  = (const float*)d_in[4];
    const float* w1     = (const float*)d_in[5];
    const float* b1     = (const float*)d_in[6];
    const float* w2     = (const float*)d_in[7];
    const float* b2     = (const float*)d_in[8];
    const float* w3     = (const float*)d_in[9];
    const float* b3     = (const float*)d_in[10];
    const float* cw1    = (const float*)d_in[11];
    const float* cb1    = (const float*)d_in[12];
    const float* cw2    = (const float*)d_in[13];
    const float* cb2    = (const float*)d_in[14];
    float* out = (float*)d_out;
    (void)in_sizes; (void)n_in; (void)out_size; (void)ws_size;

    char* ws = (char*)d_ws;
    const size_t nvhd = (size_t)NV * HD, nehd = (size_t)NE * HD;
    const size_t permsz = (size_t)(NBM_V + 1) * 2 * 256 * 64;
    size_t off = 0;
    auto alloc = [&](size_t bytes) { char* p = ws + off; off += (bytes + 255) & ~(size_t)255; return p; };
    bf16* x0 = (bf16*)alloc(nvhd * 2);
    bf16* xA = (bf16*)alloc(nvhd * 2);
    bf16* E1 = (bf16*)alloc(nehd * 2);
    bf16* E2 = (bf16*)alloc(nehd * 2);
    bf16* S  = (bf16*)alloc(permsz * 2);        // PERM layout
    bf16* z0 = (bf16*)alloc(permsz * 2);        // PERM layout
    unsigned short* W23at  = (unsigned short*)alloc(2 * 256 * 256 * 2);  // [W23at ; w3t]
    unsigned short* w3t    = W23at + 65536;
    unsigned short* W23bt  = (unsigned short*)alloc(256 * 256 * 2);
    unsigned short* W123bt = (unsigned short*)alloc(256 * 256 * 2);
    unsigned short* w2ab   = (unsigned short*)alloc(512 * 256 * 2);
    unsigned short* w2a_nb = w2ab;
    unsigned short* w2b_nb = w2ab + 256 * 256;
    unsigned short* w1_nb  = (unsigned short*)alloc(256 * 256 * 2);
    unsigned short* lin_wt = (unsigned short*)alloc(256 * 512 * 2);
    unsigned short* cw1t   = (unsigned short*)alloc(256 * 256 * 2);
    unsigned short* cw2t   = (unsigned short*)alloc(48 * 256 * 2);
    float* b2w3  = (float*)alloc(256 * 4);
    float* b1w23 = (float*)alloc(256 * 4);
    int* cnt_e = (int*)alloc(NE * 4);            // cnt_v must follow (single fill)
    int* cnt_v = (int*)alloc(NV * 4);
    int* dege2 = (int*)alloc(NV * 4);
    int* off_e = (int*)alloc((NE + 1) * 4);
    int* off_v = (int*)alloc((NV + 1) * 4);
    int* cur_e = (int*)alloc(NE * 4);
    int* cur_v = (int*)alloc(NV * 4);
    int* part_e = (int*)alloc(256 * 4);
    int* part_v = (int*)alloc(256 * 4);
    int* adj_e = (int*)alloc((size_t)NNZC * 4);
    int* adj_v = (int*)alloc((size_t)NNZC * 4);

    dim3 blk(256);
    const int gatherE_blocks = (NE + 3) / 4;    // 20000

    // ---- CSR build + weight prep (merged fill+prep) ----
    fill_prep_k<<<128 + 1841, blk, 0, stream>>>((unsigned int*)cnt_e, NE + NV,
        lin_w, w1, w2, w3, cw1, cw2, b2,
        lin_wt, w1_nb, w2a_nb, w2b_nb, w3t, cw1t, cw2t, b2w3);
    hist_k<<<(NNZC + 255) / 256, blk, 0, stream>>>(vertex, edges, cnt_v, cnt_e, NNZC);
    scan_part2_k<<<dim3(NCH_E, 2), blk, 0, stream>>>(cnt_e, off_e, part_e, cnt_v, off_v, part_v);
    scan_top2_k<<<2, blk, 0, stream>>>(part_e, off_e + NE, part_v, off_v + NV);
    scan_addcur2_k<<<dim3((NE + 255) / 256, 2), blk, 0, stream>>>(off_e, part_e, cur_e,
                                                                  off_v, part_v, cur_v);
    csr_fill_k<<<(NNZC + 255) / 256, blk, 0, stream>>>(vertex, edges, cur_e, cur_v, adj_e, adj_v, NNZC);
    dege2_k<<<(NV + 255) / 256, blk, 0, stream>>>(cnt_e, adj_v, off_v, dege2, NV);

    // ---- weight compositions ----
    mgemm_k<3, false><<<xcd_grid(256, 512), blk, 0, stream>>>((const bf16*)w3t, (const bf16*)w2ab,
        nullptr, nullptr, nullptr, nullptr, nullptr, nullptr, nullptr, nullptr,
        (bf16*)W23at, (bf16*)W23bt, nullptr, 256, 256, 512);
    mgemm_k<0, false><<<xcd_grid(256, 256), blk, 0, stream>>>((const bf16*)W23bt, (const bf16*)w1_nb,
        nullptr, nullptr, nullptr, nullptr, nullptr, nullptr, nullptr, nullptr,
        (bf16*)W123bt, nullptr, nullptr, 256, 256, 256);
    b1w23_k<<<1, blk, 0, stream>>>(b1, W23bt, b1w23);

    // ---- input projection (AF32 reg-staged) ----
    mgemm_k<1, true><<<xcd_grid(NV, 256), blk, 0, stream>>>(x_in, (const bf16*)lin_wt,
        lin_b, nullptr, nullptr, nullptr, nullptr, nullptr, nullptr, nullptr,
        x0, nullptr, nullptr, NV, FINC, HD);

    const bf16* cur = x0;
    for (int layer = 0; layer < 2; ++layer) {
        int Nc_s = (layer == 0) ? 512 : 256;            // layer0: [S|z0], layer1: S only
        int gb = xcd_grid(NV, Nc_s);
        // fused: {[S(|z0)] = cur @ [W23at(;w3t)]} || {E2 = gather_e(cur)}
        fusedA_k<<<gb + gatherE_blocks, blk, 0, stream>>>(cur, (const bf16*)W23at,
            S, z0, NV, HD, Nc_s, gb, cur, adj_e, off_e, E2, NE);
        // E1 = gather_v(E2)
        gather_sum_k<<<(NV + 3) / 4, blk, 0, stream>>>(E2, adj_v, off_v, E1, NV);
        // xA = relu(0.5*(deg*(S+b2w3) + g2cur@W123b + dege2*b1w23) + 0.5*z0 + b3)
        mgemm_k<4, false><<<xcd_grid(NV, 256), blk, 0, stream>>>(E1, (const bf16*)W123bt,
            b3, nullptr, cnt_v, dege2, S, z0, b2w3, b1w23,
            xA, nullptr, nullptr, NV, HD, HD);
        cur = xA;
    }

    // ---- classifier ----
    mgemm_k<1, false><<<xcd_grid(NV, 256), blk, 0, stream>>>(xA, (const bf16*)cw1t,
        cb1, nullptr, nullptr, nullptr, nullptr, nullptr, nullptr, nullptr,
        E1, nullptr, nullptr, NV, HD, HD);
    cls_mfma_k<<<(NV + 63) / 64, blk, 0, stream>>>(E1, (const bf16*)cw2t, cb2, out, NV);
}

// Round 15
// 481.248 us; speedup vs baseline: 1.1116x; 1.1116x over previous
//
#include <hip/hip_runtime.h>
#include <hip/hip_bf16.h>
#include <cstdint>
#include <cstddef>

#define HD   256
#define NV   50000
#define NE   80000
#define NNZC 400000
#define FINC 512
#define NCLS 40

using bf16 = __hip_bfloat16;

typedef short bf16x8v __attribute__((ext_vector_type(8)));
typedef float f32x4   __attribute__((ext_vector_type(4)));
typedef unsigned short u16x8 __attribute__((ext_vector_type(8)));

#define NCH_E ((NE + 1023) / 1024)   // 79
#define NCH_V ((NV + 1023) / 1024)   // 49
#define NBM_V ((NV + 127) / 128)     // 391

// ---------- dtype helpers ----------
__device__ __forceinline__ float b2f(unsigned short u) {
    union { unsigned int i; float f; } c; c.i = ((unsigned int)u) << 16; return c.f;
}
__device__ __forceinline__ unsigned short f2b(float f) {
    union { float f; unsigned int i; } c; c.f = f;
    return (unsigned short)((c.i + 0x7FFFu + ((c.i >> 16) & 1u)) >> 16);
}
__device__ __forceinline__ float4 load4f(const bf16* p) {
    ushort4 u = *reinterpret_cast<const ushort4*>(p);
    return make_float4(b2f(u.x), b2f(u.y), b2f(u.z), b2f(u.w));
}
__device__ __forceinline__ void store4(bf16* p, float4 v) {
    ushort4 u; u.x = f2b(v.x); u.y = f2b(v.y); u.z = f2b(v.z); u.w = f2b(v.w);
    *reinterpret_cast<ushort4*>(p) = u;
}

// ---------- async global->LDS, 16B per lane (bf16 staging only; r6 lesson) ----------
__device__ __forceinline__ void gl_lds16(const bf16* g, short* l) {
    __builtin_amdgcn_global_load_lds(
        (const __attribute__((address_space(1))) unsigned int*)g,
        (__attribute__((address_space(3))) unsigned int*)l,
        16, 0, 0);
}

// ---------- merged capture-safe fill + weight prep ----------
__global__ __launch_bounds__(256)
void fill_prep_k(unsigned int* __restrict__ fillp, long long filln,
                 const float* __restrict__ lin_w, const float* __restrict__ w1,
                 const float* __restrict__ w2, const float* __restrict__ w3,
                 const float* __restrict__ cw1, const float* __restrict__ cw2,
                 const float* __restrict__ b2,
                 unsigned short* __restrict__ lin_wt, unsigned short* __restrict__ w1_nb,
                 unsigned short* __restrict__ w2a_nb, unsigned short* __restrict__ w2b_nb,
                 unsigned short* __restrict__ w3t, unsigned short* __restrict__ cw1t,
                 unsigned short* __restrict__ cw2t, float* __restrict__ b2w3)
{
    if (blockIdx.x < 128) {
        long long i = (long long)blockIdx.x * 256 + threadIdx.x;
        for (; i < filln; i += 128 * 256) fillp[i] = 0u;
        return;
    }
    int idx = (blockIdx.x - 128) * 256 + threadIdx.x;
    if (idx < 131072) { int n = idx >> 9, k = idx & 511; lin_wt[idx] = f2b(lin_w[k * 256 + n]); return; }
    idx -= 131072;
    if (idx < 65536) { w1_nb[idx] = f2b(w1[idx]); return; }
    idx -= 65536;
    if (idx < 65536) { w2a_nb[idx] = f2b(w2[idx]); return; }
    idx -= 65536;
    if (idx < 65536) { w2b_nb[idx] = f2b(w2[65536 + idx]); return; }
    idx -= 65536;
    if (idx < 65536) { int n = idx >> 8, k = idx & 255; w3t[idx] = f2b(w3[k * 256 + n]); return; }
    idx -= 65536;
    if (idx < 65536) { int n = idx >> 8, k = idx & 255; cw1t[idx] = f2b(cw1[k * 256 + n]); return; }
    idx -= 65536;
    if (idx < 12288) { int n = idx >> 8, k = idx & 255; cw2t[idx] = f2b((n < NCLS) ? cw2[k * NCLS + n] : 0.f); return; }
    idx -= 12288;
    if (idx < 256) {
        float s = 0.f;
        for (int k = 0; k < 256; ++k) s += b2[k] * w3[k * 256 + idx];
        b2w3[idx] = s;
    }
}

// ---------- combined histogram ----------
__global__ __launch_bounds__(256)
void hist_k(const int* __restrict__ vertex, const int* __restrict__ edges,
            int* __restrict__ cnt_v, int* __restrict__ cnt_e, int nnz)
{
    int i = blockIdx.x * 256 + threadIdx.x;
    if (i < nnz) {
        atomicAdd(&cnt_v[vertex[i]], 1);
        atomicAdd(&cnt_e[edges[i]], 1);
    }
}

// ---------- merged 3-phase scan ----------
__global__ __launch_bounds__(256)
void scan_part2_k(const int* __restrict__ cnt_e, int* __restrict__ off_e, int* __restrict__ part_e,
                  const int* __restrict__ cnt_v, int* __restrict__ off_v, int* __restrict__ part_v)
{
    const int* cnt; int* off; int* part; int n;
    if (blockIdx.y == 0) { cnt = cnt_e; off = off_e; part = part_e; n = NE; }
    else                 { cnt = cnt_v; off = off_v; part = part_v; n = NV; }
    int base = blockIdx.x * 1024;
    if (base >= n) return;
    __shared__ int s[256];
    int idx = base + threadIdx.x * 4;
    int v[4], sum = 0;
    #pragma unroll
    for (int j = 0; j < 4; ++j) { v[j] = (idx + j < n) ? cnt[idx + j] : 0; sum += v[j]; }
    s[threadIdx.x] = sum;
    __syncthreads();
    #pragma unroll
    for (int d = 1; d < 256; d <<= 1) {
        int t = (threadIdx.x >= d) ? s[threadIdx.x - d] : 0;
        __syncthreads();
        s[threadIdx.x] += t;
        __syncthreads();
    }
    int excl = s[threadIdx.x] - sum;
    #pragma unroll
    for (int j = 0; j < 4; ++j) {
        if (idx + j < n) off[idx + j] = excl;
        excl += v[j];
    }
    if (threadIdx.x == 255) part[blockIdx.x] = s[255];
}

__global__ __launch_bounds__(256)
void scan_top2_k(int* __restrict__ part_e, int* __restrict__ end_e,
                 int* __restrict__ part_v, int* __restrict__ end_v)
{
    int* part; int* endp; int nch;
    if (blockIdx.x == 0) { part = part_e; endp = end_e; nch = NCH_E; }
    else                 { part = part_v; endp = end_v; nch = NCH_V; }
    __shared__ int s[256];
    int v = (threadIdx.x < nch) ? part[threadIdx.x] : 0;
    s[threadIdx.x] = v;
    __syncthreads();
    #pragma unroll
    for (int d = 1; d < 256; d <<= 1) {
        int t = (threadIdx.x >= d) ? s[threadIdx.x - d] : 0;
        __syncthreads();
        s[threadIdx.x] += t;
        __syncthreads();
    }
    if (threadIdx.x < nch) part[threadIdx.x] = s[threadIdx.x] - v;
    if (threadIdx.x == 255) *endp = s[255];
}

__global__ __launch_bounds__(256)
void scan_addcur2_k(int* __restrict__ off_e, const int* __restrict__ part_e, int* __restrict__ cur_e,
                    int* __restrict__ off_v, const int* __restrict__ part_v, int* __restrict__ cur_v)
{
    int n; int* off; const int* part; int* cur;
    if (blockIdx.y == 0) { n = NE; off = off_e; part = part_e; cur = cur_e; }
    else                 { n = NV; off = off_v; part = part_v; cur = cur_v; }
    int i = blockIdx.x * 256 + threadIdx.x;
    if (i < n) { int o = off[i] + part[i >> 10]; off[i] = o; cur[i] = o; }
}

// ---------- CSR adjacency fill ----------
__global__ __launch_bounds__(256)
void csr_fill_k(const int* __restrict__ vertex, const int* __restrict__ edges,
                int* __restrict__ cur_e, int* __restrict__ cur_v,
                int* __restrict__ adj_e, int* __restrict__ adj_v, int nnz)
{
    int i = blockIdx.x * 256 + threadIdx.x;
    if (i >= nnz) return;
    int v = vertex[i], e = edges[i];
    adj_e[atomicAdd(&cur_e[e], 1)] = v;
    adj_v[atomicAdd(&cur_v[v], 1)] = e;
}

// ---------- dege2[v] = sum_{e in adj_v[v]} cnt_e[e] ----------
__global__ __launch_bounds__(256)
void dege2_k(const int* __restrict__ cnt_e, const int* __restrict__ adj_v,
             const int* __restrict__ off_v, int* __restrict__ dege2, int n)
{
    int v = blockIdx.x * 256 + threadIdx.x;
    if (v >= n) return;
    int s = 0;
    for (int j = off_v[v]; j < off_v[v + 1]; ++j) s += cnt_e[adj_v[j]];
    dege2[v] = s;
}

// ---------- b1w23[n] = sum_k b1[k] * W23b[k][n] ----------
__global__ __launch_bounds__(256)
void b1w23_k(const float* __restrict__ b1, const unsigned short* __restrict__ W23bt,
             float* __restrict__ o)
{
    int n = threadIdx.x;
    float s = 0.f;
    for (int k = 0; k < 256; ++k) s += b1[k] * b2f(W23bt[n * 256 + k]);
    o[n] = s;
}

// ---------- MFMA bf16 GEMM: 128x128 tile, BK=64, 4 waves, 2-PHASE DBUF (r15) ----------
// XCD-grouped grid + both-sides swizzle (r8/r9). STAGE(next) issued before
// ds_read+MFMA of current; one __syncthreads per K-step (drains vmcnt+lgkm).
// EPI 0/1: row-major (+bias)(+relu). EPI 3: row-major multi-split.
// EPI 5: PERM split store. EPI 4: perm S/z0 hoisted before K-loop.
template<int EPI, bool AF32>
__global__ __launch_bounds__(256)
void mgemm_k(const void* __restrict__ Agv, const bf16* __restrict__ Bt,
             const float* __restrict__ bias, const float* __restrict__ bias2,
             const int* __restrict__ deg, const int* __restrict__ dege2,
             const bf16* __restrict__ Sb, const bf16* __restrict__ z0b,
             const float* __restrict__ b2w3v, const float* __restrict__ b1w23v,
             bf16* __restrict__ Cg, bf16* __restrict__ Cg2, bf16* __restrict__ Cg3,
             int M, int K, int Nc)
{
    const int nbn = Nc >> 7;
    const int nbm = (M + 127) >> 7;
    const int p   = blockIdx.x;
    const int xcd = p & 7;
    const int q   = p >> 3;
    const int cblk = q % nbn;
    const int rblk = q / nbn;
    const int rb   = rblk * 8 + xcd;
    if (rb >= nbm) return;
    const int bn = cblk * 128;
    const int bm = rb * 128;

    __shared__ __align__(16) short As[2][128 * 64];   // 64 KB total with Bs
    __shared__ __align__(16) short Bs[2][128 * 64];

    const int t  = threadIdx.x;
    const int wv = t >> 6, l = t & 63;
    const int wr = wv >> 1, wc = wv & 1;
    const int l15 = l & 15;

    // ---- EPI4: S/z0 perm loads + bias loads issued EARLY ----
    u16x8 sv8[8], zv8[8];
    float bv[4], bw[4], bb1[4];
    if (EPI == 4) {
        const unsigned short* Sp = (const unsigned short*)Sb + ((size_t)(rb * 2 + cblk) * 256 + t) * 64;
        const unsigned short* Zp = (const unsigned short*)z0b + ((size_t)(rb * 2 + cblk) * 256 + t) * 64;
        #pragma unroll
        for (int j = 0; j < 8; ++j) {
            sv8[j] = *reinterpret_cast<const u16x8*>(Sp + j * 8);
            zv8[j] = *reinterpret_cast<const u16x8*>(Zp + j * 8);
        }
        #pragma unroll
        for (int n = 0; n < 4; ++n) {
            int col = bn + wc * 64 + n * 16 + l15;
            bv[n]  = bias[col];
            bw[n]  = b2w3v[col];
            bb1[n] = b1w23v[col];
        }
    }

    f32x4 acc[4][4];
    #pragma unroll
    for (int m = 0; m < 4; ++m)
        #pragma unroll
        for (int n = 0; n < 4; ++n)
            acc[m][n] = (f32x4){0.f, 0.f, 0.f, 0.f};

    const int brow8   = l >> 3;
    const int bcol_sw = (((l & 7) ^ (l >> 3)) * 8);

    auto stage = [&](int buf, int k0) {
        if constexpr (AF32) {
            const float* Af = (const float*)Agv;
            #pragma unroll
            for (int pi = 0; pi < 4; ++pi) {
                int idx8 = pi * 256 + t;
                int row  = idx8 >> 3;
                int cg   = (idx8 & 7) * 8;
                int ga = bm + row; if (ga >= M) ga = M - 1;
                const float* src = Af + (size_t)ga * K + k0 + cg;
                f32x4 u = *reinterpret_cast<const f32x4*>(src);
                f32x4 v = *reinterpret_cast<const f32x4*>(src + 4);
                bf16x8v o;
                o[0] = (short)f2b(u[0]); o[1] = (short)f2b(u[1]);
                o[2] = (short)f2b(u[2]); o[3] = (short)f2b(u[3]);
                o[4] = (short)f2b(v[0]); o[5] = (short)f2b(v[1]);
                o[6] = (short)f2b(v[2]); o[7] = (short)f2b(v[3]);
                *reinterpret_cast<bf16x8v*>(&As[buf][row * 64 + (cg ^ ((row & 7) * 8))]) = o;
            }
        } else {
            const bf16* Ab = (const bf16*)Agv;
            #pragma unroll
            for (int i = 0; i < 4; ++i) {
                int c = wv * 4 + i;
                int row = c * 8 + brow8;
                int ga = bm + row; if (ga >= M) ga = M - 1;
                gl_lds16(Ab + (size_t)ga * K + k0 + bcol_sw, &As[buf][c * 512]);
            }
        }
        #pragma unroll
        for (int i = 0; i < 4; ++i) {
            int c = wv * 4 + i;
            int row = c * 8 + brow8;
            gl_lds16(Bt + (size_t)(bn + row) * K + k0 + bcol_sw, &Bs[buf][c * 512]);
        }
    };

    // ---- 2-phase pipelined K-loop ----
    stage(0, 0);
    __syncthreads();
    const int nk = K >> 6;
    for (int kst = 0; kst < nk; ++kst) {
        int curb = kst & 1;
        if (kst + 1 < nk) stage(curb ^ 1, (kst + 1) * 64);   // prefetch next tile
        #pragma unroll
        for (int ks = 0; ks < 2; ++ks) {
            bf16x8v a[4], b[4];
            const int kb = ks * 64 + (l >> 4) * 16;
            #pragma unroll
            for (int m = 0; m < 4; ++m) {
                int r = wr * 64 + m * 16 + l15;
                a[m] = *reinterpret_cast<const bf16x8v*>(
                           (const char*)&As[curb][0] + r * 128 + (kb ^ ((r & 7) << 4)));
            }
            #pragma unroll
            for (int n = 0; n < 4; ++n) {
                int r = wc * 64 + n * 16 + l15;
                b[n] = *reinterpret_cast<const bf16x8v*>(
                           (const char*)&Bs[curb][0] + r * 128 + (kb ^ ((r & 7) << 4)));
            }
            #pragma unroll
            for (int m = 0; m < 4; ++m)
                #pragma unroll
                for (int n = 0; n < 4; ++n)
                    acc[m][n] = __builtin_amdgcn_mfma_f32_16x16x32_bf16(a[m], b[n], acc[m][n], 0, 0, 0);
        }
        __syncthreads();   // drains next-tile loads (covered by MFMA above) + ds reads
    }

    if (EPI == 5) {
        int oi = bn >> 8;
        bf16* CC = (oi == 0) ? Cg : Cg2;
        int c2 = (bn >> 7) & 1;
        unsigned short* P = (unsigned short*)CC + ((size_t)(rb * 2 + c2) * 256 + t) * 64;
        #pragma unroll
        for (int m = 0; m < 4; ++m) {
            u16x8 o0, o1;
            #pragma unroll
            for (int n = 0; n < 2; ++n)
                #pragma unroll
                for (int i = 0; i < 4; ++i) {
                    o0[n * 4 + i] = f2b(acc[m][n][i]);
                    o1[n * 4 + i] = f2b(acc[m][n + 2][i]);
                }
            *reinterpret_cast<u16x8*>(P + m * 16)     = o0;
            *reinterpret_cast<u16x8*>(P + m * 16 + 8) = o1;
        }
    } else if (EPI == 4) {
        #pragma unroll
        for (int m = 0; m < 4; ++m) {
            #pragma unroll
            for (int i = 0; i < 4; ++i) {
                int row = bm + wr * 64 + m * 16 + (l >> 4) * 4 + i;
                if (row >= M) continue;
                float d   = (float)deg[row];
                float de2 = (float)dege2[row];
                size_t base = (size_t)row * Nc + bn + wc * 64 + l15;
                #pragma unroll
                for (int n = 0; n < 4; ++n) {
                    int e = m * 16 + n * 4 + i;
                    float sv = b2f(sv8[e >> 3][e & 7]);
                    float zv = b2f(zv8[e >> 3][e & 7]);
                    float v = 0.5f * (d * (sv + bw[n]) + acc[m][n][i] + de2 * bb1[n])
                              + 0.5f * zv + bv[n];
                    v = fmaxf(v, 0.f);
                    reinterpret_cast<unsigned short*>(Cg)[base + (size_t)n * 16] = f2b(v);
                }
            }
        }
    } else if (EPI == 3) {
        int oi = bn >> 8;
        bf16* CC = (oi == 0) ? Cg : (oi == 1) ? Cg2 : Cg3;
        const float* bb = (oi == 0) ? bias : (oi == 1) ? bias2 : nullptr;
        int cb = bn & 255;
        float bvv[4];
        #pragma unroll
        for (int n = 0; n < 4; ++n)
            bvv[n] = bb ? bb[cb + wc * 64 + n * 16 + l15] : 0.f;
        #pragma unroll
        for (int m = 0; m < 4; ++m) {
            #pragma unroll
            for (int i = 0; i < 4; ++i) {
                int row = bm + wr * 64 + m * 16 + (l >> 4) * 4 + i;
                if (row >= M) continue;
                size_t base = (size_t)row * 256 + cb + wc * 64 + l15;
                #pragma unroll
                for (int n = 0; n < 4; ++n)
                    reinterpret_cast<unsigned short*>(CC)[base + n * 16] = f2b(acc[m][n][i] + bvv[n]);
            }
        }
    } else {
        float bvv[4];
        #pragma unroll
        for (int n = 0; n < 4; ++n)
            bvv[n] = bias ? bias[bn + wc * 64 + n * 16 + l15] : 0.f;
        #pragma unroll
        for (int m = 0; m < 4; ++m) {
            #pragma unroll
            for (int i = 0; i < 4; ++i) {
                int row = bm + wr * 64 + m * 16 + (l >> 4) * 4 + i;
                if (row >= M) continue;
                size_t base = (size_t)row * Nc + bn + wc * 64 + l15;
                #pragma unroll
                for (int n = 0; n < 4; ++n) {
                    float v = acc[m][n][i] + bvv[n];
                    if (EPI == 1) v = fmaxf(v, 0.f);
                    reinterpret_cast<unsigned short*>(Cg)[base + n * 16] = f2b(v);
                }
            }
        }
    }
}

// ---------- gather segment-sum ----------
__global__ __launch_bounds__(256)
void gather_sum_k(const bf16* __restrict__ src, const int* __restrict__ adj,
                  const int* __restrict__ off, bf16* __restrict__ dst, int nseg)
{
    int seg = blockIdx.x * 4 + (threadIdx.x >> 6);
    if (seg >= nseg) return;
    int lane = threadIdx.x & 63;
    int s0 = off[seg], s1 = off[seg + 1];
    float4 acc = make_float4(0.f, 0.f, 0.f, 0.f);
    int j = s0;
    for (; j + 4 <= s1; j += 4) {
        int r0 = adj[j], r1 = adj[j + 1], r2 = adj[j + 2], r3 = adj[j + 3];
        float4 v0 = load4f(src + (size_t)r0 * HD + lane * 4);
        float4 v1 = load4f(src + (size_t)r1 * HD + lane * 4);
        float4 v2 = load4f(src + (size_t)r2 * HD + lane * 4);
        float4 v3 = load4f(src + (size_t)r3 * HD + lane * 4);
        acc.x += (v0.x + v1.x) + (v2.x + v3.x);
        acc.y += (v0.y + v1.y) + (v2.y + v3.y);
        acc.z += (v0.z + v1.z) + (v2.z + v3.z);
        acc.w += (v0.w + v1.w) + (v2.w + v3.w);
    }
    for (; j < s1; ++j) {
        float4 v = load4f(src + (size_t)adj[j] * HD + lane * 4);
        acc.x += v.x; acc.y += v.y; acc.z += v.z; acc.w += v.w;
    }
    store4(dst + (size_t)seg * HD + lane * 4, acc);
}

// ---------- MFMA classifier ----------
__global__ __launch_bounds__(256)
void cls_mfma_k(const bf16* __restrict__ Hm, const bf16* __restrict__ Wt,
                const float* __restrict__ bias, float* __restrict__ out, int M)
{
    const int wv = threadIdx.x >> 6, l = threadIdx.x & 63;
    const int l15 = l & 15;
    const int r0 = blockIdx.x * 64 + wv * 16;
    f32x4 acc[3];
    #pragma unroll
    for (int n = 0; n < 3; ++n) acc[n] = (f32x4){0.f, 0.f, 0.f, 0.f};

    int arow = r0 + l15; if (arow >= M) arow = M - 1;
    const int ko = (l >> 4) * 8;
    for (int kk = 0; kk < HD; kk += 32) {
        bf16x8v a = *reinterpret_cast<const bf16x8v*>(Hm + (size_t)arow * HD + kk + ko);
        #pragma unroll
        for (int n = 0; n < 3; ++n) {
            bf16x8v b = *reinterpret_cast<const bf16x8v*>(Wt + (size_t)(n * 16 + l15) * HD + kk + ko);
            acc[n] = __builtin_amdgcn_mfma_f32_16x16x32_bf16(a, b, acc[n], 0, 0, 0);
        }
    }
    #pragma unroll
    for (int n = 0; n < 3; ++n) {
        int col = n * 16 + l15;
        if (col >= NCLS) continue;
        float bv = bias[col];
        #pragma unroll
        for (int i = 0; i < 4; ++i) {
            int row = r0 + (l >> 4) * 4 + i;
            if (row < M) out[(size_t)row * NCLS + col] = acc[n][i] + bv;
        }
    }
}

static inline int xcd_grid(int M, int Nc)
{
    int nbm = (M + 127) >> 7;
    int nbn = Nc >> 7;
    return nbn * (((nbm + 7) / 8) * 8);
}

extern "C" void kernel_launch(void* const* d_in, const int* in_sizes, int n_in,
                              void* d_out, int out_size, void* d_ws, size_t ws_size,
                              hipStream_t stream)
{
    const float* x_in   = (const float*)d_in[0];
    const int*   vertex = (const int*)d_in[1];
    const int*   edges  = (const int*)d_in[2];
    const float* lin_w  = (const float*)d_in[3];
    const float* lin_b  = (const float*)d_in[4];
    const float* w1     = (const float*)d_in[5];
    const float* b1     = (const float*)d_in[6];
    const float* w2     = (const float*)d_in[7];
    const float* b2     = (const float*)d_in[8];
    const float* w3     = (const float*)d_in[9];
    const float* b3     = (const float*)d_in[10];
    const float* cw1    = (const float*)d_in[11];
    const float* cb1    = (const float*)d_in[12];
    const float* cw2    = (const float*)d_in[13];
    const float* cb2    = (const float*)d_in[14];
    float* out = (float*)d_out;
    (void)in_sizes; (void)n_in; (void)out_size; (void)ws_size;

    char* ws = (char*)d_ws;
    const size_t nvhd = (size_t)NV * HD, nehd = (size_t)NE * HD;
    const size_t permsz = (size_t)(NBM_V + 1) * 2 * 256 * 64;
    size_t off = 0;
    auto alloc = [&](size_t bytes) { char* p = ws + off; off += (bytes + 255) & ~(size_t)255; return p; };
    bf16* x0 = (bf16*)alloc(nvhd * 2);
    bf16* xA = (bf16*)alloc(nvhd * 2);
    bf16* E1 = (bf16*)alloc(nehd * 2);
    bf16* E2 = (bf16*)alloc(nehd * 2);
    bf16* S  = (bf16*)alloc(permsz * 2);        // PERM layout
    bf16* z0 = (bf16*)alloc(permsz * 2);        // PERM layout
    unsigned short* W23at  = (unsigned short*)alloc(2 * 256 * 256 * 2);  // [W23at ; w3t]
    unsigned short* w3t    = W23at + 65536;
    unsigned short* W23bt  = (unsigned short*)alloc(256 * 256 * 2);
    unsigned short* W123bt = (unsigned short*)alloc(256 * 256 * 2);
    unsigned short* w2ab   = (unsigned short*)alloc(512 * 256 * 2);
    unsigned short* w2a_nb = w2ab;
    unsigned short* w2b_nb = w2ab + 256 * 256;
    unsigned short* w1_nb  = (unsigned short*)alloc(256 * 256 * 2);
    unsigned short* lin_wt = (unsigned short*)alloc(256 * 512 * 2);
    unsigned short* cw1t   = (unsigned short*)alloc(256 * 256 * 2);
    unsigned short* cw2t   = (unsigned short*)alloc(48 * 256 * 2);
    float* b2w3  = (float*)alloc(256 * 4);
    float* b1w23 = (float*)alloc(256 * 4);
    int* cnt_e = (int*)alloc(NE * 4);            // cnt_v must follow (single fill)
    int* cnt_v = (int*)alloc(NV * 4);
    int* dege2 = (int*)alloc(NV * 4);
    int* off_e = (int*)alloc((NE + 1) * 4);
    int* off_v = (int*)alloc((NV + 1) * 4);
    int* cur_e = (int*)alloc(NE * 4);
    int* cur_v = (int*)alloc(NV * 4);
    int* part_e = (int*)alloc(256 * 4);
    int* part_v = (int*)alloc(256 * 4);
    int* adj_e = (int*)alloc((size_t)NNZC * 4);
    int* adj_v = (int*)alloc((size_t)NNZC * 4);

    dim3 blk(256);

    // ---- CSR build + weight prep ----
    fill_prep_k<<<128 + 1841, blk, 0, stream>>>((unsigned int*)cnt_e, NE + NV,
        lin_w, w1, w2, w3, cw1, cw2, b2,
        lin_wt, w1_nb, w2a_nb, w2b_nb, w3t, cw1t, cw2t, b2w3);
    hist_k<<<(NNZC + 255) / 256, blk, 0, stream>>>(vertex, edges, cnt_v, cnt_e, NNZC);
    scan_part2_k<<<dim3(NCH_E, 2), blk, 0, stream>>>(cnt_e, off_e, part_e, cnt_v, off_v, part_v);
    scan_top2_k<<<2, blk, 0, stream>>>(part_e, off_e + NE, part_v, off_v + NV);
    scan_addcur2_k<<<dim3((NE + 255) / 256, 2), blk, 0, stream>>>(off_e, part_e, cur_e,
                                                                  off_v, part_v, cur_v);
    csr_fill_k<<<(NNZC + 255) / 256, blk, 0, stream>>>(vertex, edges, cur_e, cur_v, adj_e, adj_v, NNZC);
    dege2_k<<<(NV + 255) / 256, blk, 0, stream>>>(cnt_e, adj_v, off_v, dege2, NV);

    // ---- weight compositions ----
    mgemm_k<3, false><<<xcd_grid(256, 512), blk, 0, stream>>>((const bf16*)w3t, (const bf16*)w2ab,
        nullptr, nullptr, nullptr, nullptr, nullptr, nullptr, nullptr, nullptr,
        (bf16*)W23at, (bf16*)W23bt, nullptr, 256, 256, 512);
    mgemm_k<0, false><<<xcd_grid(256, 256), blk, 0, stream>>>((const bf16*)W23bt, (const bf16*)w1_nb,
        nullptr, nullptr, nullptr, nullptr, nullptr, nullptr, nullptr, nullptr,
        (bf16*)W123bt, nullptr, nullptr, 256, 256, 256);
    b1w23_k<<<1, blk, 0, stream>>>(b1, W23bt, b1w23);

    // ---- input projection (AF32 reg-staged) ----
    mgemm_k<1, true><<<xcd_grid(NV, 256), blk, 0, stream>>>(x_in, (const bf16*)lin_wt,
        lin_b, nullptr, nullptr, nullptr, nullptr, nullptr, nullptr, nullptr,
        x0, nullptr, nullptr, NV, FINC, HD);

    const bf16* cur = x0;
    for (int layer = 0; layer < 2; ++layer) {
        if (layer == 0) {
            // [S | z0] = x0 @ [W23at ; w3t]   (dual GEMM, PERM stores)
            mgemm_k<5, false><<<xcd_grid(NV, 512), blk, 0, stream>>>(cur, (const bf16*)W23at,
                nullptr, nullptr, nullptr, nullptr, nullptr, nullptr, nullptr, nullptr,
                S, z0, nullptr, NV, HD, 512);
        } else {
            // S = cur @ W23at   (PERM store)
            mgemm_k<5, false><<<xcd_grid(NV, 256), blk, 0, stream>>>(cur, (const bf16*)W23at,
                nullptr, nullptr, nullptr, nullptr, nullptr, nullptr, nullptr, nullptr,
                S, nullptr, nullptr, NV, HD, HD);
        }
        // E2 = gather_e(cur); E1 = gather_v(E2)
        gather_sum_k<<<(NE + 3) / 4, blk, 0, stream>>>(cur, adj_e, off_e, E2, NE);
        gather_sum_k<<<(NV + 3) / 4, blk, 0, stream>>>(E2, adj_v, off_v, E1, NV);
        // xA = relu(0.5*(deg*(S+b2w3) + g2cur@W123b + dege2*b1w23) + 0.5*z0 + b3)
        mgemm_k<4, false><<<xcd_grid(NV, 256), blk, 0, stream>>>(E1, (const bf16*)W123bt,
            b3, nullptr, cnt_v, dege2, S, z0, b2w3, b1w23,
            xA, nullptr, nullptr, NV, HD, HD);
        cur = xA;
    }

    // ---- classifier ----
    mgemm_k<1, false><<<xcd_grid(NV, 256), blk, 0, stream>>>(xA, (const bf16*)cw1t,
        cb1, nullptr, nullptr, nullptr, nullptr, nullptr, nullptr, nullptr,
        E1, nullptr, nullptr, NV, HD, HD);
    cls_mfma_k<<<(NV + 63) / 64, blk, 0, stream>>>(E1, (const bf16*)cw2t, cb2, out, NV);
}